// Round 2
// baseline (540.585 us; speedup 1.0000x reference)
//
#include <hip/hip_runtime.h>
#include <cstdint>
#include <cstddef>

// Problem constants (B=4, V=64, E=1024, L=1024, D=256, DEG=16)
constexpr int Bv = 4;
constexpr int Ev = 1024;      // edges per batch
constexpr int Lv = 1024;
constexpr int BE = Bv * Ev;   // 4096
constexpr size_t EI_PLANE = (size_t)BE * Lv;  // 4,194,304 elements per ei plane

// bf16 LDS row stride for hs tile: 256 + 8 pad -> 528 B rows (16B aligned;
// b128 fragment reads land 2-way on banks = free)
constexpr int STRB = 264;
// per-wave private T row stride (bf16): 32 cols + 8 pad = 40 -> 80 B rows
constexpr int TW = 40;

typedef __bf16 bf16x8 __attribute__((ext_vector_type(8)));
typedef __bf16 bf16x4 __attribute__((ext_vector_type(4)));
typedef float  f32x4  __attribute__((ext_vector_type(4)));

// ---------------------------------------------------------------------------
// Precompute (grid 257 x 256 threads):
//  blocks 0..255: tile (i = blk>>4, j = blk&15) of M' = (Wq^T Wk) / 16,
//    bf16, written pre-swizzled to MFMA B-fragment layout:
//      for element (d, t):  f = (d>>5)*16 + (t>>4);
//                           lane = ((d>>3)&3)*16 + (t&15); jj = d&7;
//      Mb[(f*64 + lane)*8 + jj] = M'[d][t]
//  block 256: rv[t] = (sum_i bq[i] * Wk[i*256+t]) / 16  (fp32)
//  (bk and the h_src-only bias terms cancel in the softmax -> never computed;
//   the 1/sqrt(D)=1/16 logit scale is folded in here.)
// ---------------------------------------------------------------------------
__global__ __launch_bounds__(256) void precompute_kernel(
    const float* __restrict__ Wq, const float* __restrict__ Wk,
    const float* __restrict__ bq, __bf16* __restrict__ Mb, float* __restrict__ rv)
{
    const int blk = blockIdx.x;
    const int tid = threadIdx.x;
    if (blk < 256) {
        __shared__ float qs[256 * 17];
        __shared__ float ks[256 * 17];
        const int i16 = (blk >> 4) * 16;   // d-tile base
        const int j16 = (blk & 15) * 16;   // t-tile base
        const int c  = tid & 15;
        const int r0 = tid >> 4;
        #pragma unroll
        for (int it = 0; it < 16; ++it) {
            const int r = it * 16 + r0;
            qs[r * 17 + c] = Wq[r * 256 + i16 + c];
            ks[r * 17 + c] = Wk[r * 256 + j16 + c];
        }
        __syncthreads();
        const int dd = tid >> 4;   // 0..15 local d
        const int tt = tid & 15;   // 0..15 local t
        float a0 = 0.f, a1 = 0.f, a2 = 0.f, a3 = 0.f;
        for (int r = 0; r < 256; r += 4) {
            a0 = fmaf(qs[(r + 0) * 17 + dd], ks[(r + 0) * 17 + tt], a0);
            a1 = fmaf(qs[(r + 1) * 17 + dd], ks[(r + 1) * 17 + tt], a1);
            a2 = fmaf(qs[(r + 2) * 17 + dd], ks[(r + 2) * 17 + tt], a2);
            a3 = fmaf(qs[(r + 3) * 17 + dd], ks[(r + 3) * 17 + tt], a3);
        }
        const float m = ((a0 + a1) + (a2 + a3)) * 0.0625f;
        const int d = i16 + dd, t = j16 + tt;
        const int f    = (d >> 5) * 16 + (t >> 4);
        const int lane = ((d >> 3) & 3) * 16 + (t & 15);
        const int jj   = d & 7;
        Mb[((size_t)f * 64 + lane) * 8 + jj] = (__bf16)m;
    } else {
        __shared__ float bqs[256];
        bqs[tid] = bq[tid];
        __syncthreads();
        float a0 = 0.f, a1 = 0.f;
        for (int i = 0; i < 256; i += 2) {
            a0 = fmaf(bqs[i + 0], Wk[(i + 0) * 256 + tid], a0);
            a1 = fmaf(bqs[i + 1], Wk[(i + 1) * 256 + tid], a1);
        }
        rv[tid] = (a0 + a1) * 0.0625f;
    }
}

// ---------------------------------------------------------------------------
// Main fused kernel, barrier-free compute phase. One block (4 waves) per (b,l).
//   LDS = hs (33.8 KB) + 4 private T regions (20 KB) = 54.3 KB -> 3 blocks/CU.
//  1) stage A = hs[b,:,l,:] (64x256) as bf16 in LDS (16B LDS stores); barrier.
//  2) per wave, FULLY independent (no barriers), cch loop ROLLED to bound
//     the scheduling window (register pressure, avoid spills under the
//     (256,3) VGPR cap of 168):
//     for chunk c in {0,1}: wave w owns t-slice [c*128 + w*32, +32):
//       GEMM1: T_w = A @ M'[:, slice] + r'   (4m x 2n x 8k = 64 MFMA)
//       write T_w to the wave's PRIVATE LDS region (same-wave ordering only)
//       GEMM2 k-split partial over this slice, BAND-ONLY n-tiles
//         {mt, (mt+1)&3} (edge struct: dst in src+1..src+16 mod 64): 8 MFMA
//  3) cross-wave reduce of 4 partial band-S (4 cheap barriers).
//  4) per-edge logits from band-S, group-of-16 softmax via shfl, write probs
//     (or scattered ew_out directly if !USE_WS)
// ---------------------------------------------------------------------------
template <bool USE_WS>
__global__ __launch_bounds__(256, 3) void edge_main(
    const float* __restrict__ hs, const int* __restrict__ eidx,
    const float* __restrict__ ew, const float* __restrict__ skipp,
    const __bf16* __restrict__ Mb, const float* __restrict__ rv,
    float* __restrict__ probs_or_out)
{
    __shared__ __bf16 hs_s[64 * STRB];          // 33792 B
    __shared__ __bf16 Tw_all[4 * 64 * TW];      // 20480 B (4 x 5120 B private)
    float* S0 = (float*)Tw_all;                 // band-S 64 x 36 f32 (9216 B)
    float* S1 = S0 + 2304;                      // second partial (9216 B)

    const int bl = blockIdx.x;          // 0..4095
    const int b  = bl >> 10;
    const int l  = bl & 1023;
    const int tid  = threadIdx.x;
    const int w    = tid >> 6;          // wave 0..3
    const int lane = tid & 63;
    const int l15  = lane & 15;
    const int quad = lane >> 4;

    // ---- stage hs tile (64 rows x 256 cols fp32 -> bf16), coalesced ----
    // Each lane owns 8 consecutive floats of one row -> one 16B LDS store.
    {
        const float* base = hs + ((size_t)b * 64 * 1024 + (size_t)l) * 256;
        const int half = lane >> 5;          // 0..1
        const int c8   = (lane & 31) * 8;    // col base
        #pragma unroll
        for (int k = 0; k < 8; ++k) {
            const int v = k * 8 + w * 2 + half;
            const float* p = base + (size_t)v * (1024 * 256) + c8;
            float4 va = *(const float4*)p;
            float4 vb = *(const float4*)(p + 4);
            bf16x8 h;
            h[0] = (__bf16)va.x; h[1] = (__bf16)va.y;
            h[2] = (__bf16)va.z; h[3] = (__bf16)va.w;
            h[4] = (__bf16)vb.x; h[5] = (__bf16)vb.y;
            h[6] = (__bf16)vb.z; h[7] = (__bf16)vb.w;
            *(bf16x8*)(&hs_s[v * STRB + c8]) = h;
        }
    }
    __syncthreads();

    // band-S accumulators: s_acc[mt][slot]; slot 0 -> n-tile mt, 1 -> (mt+1)&3
    f32x4 s_acc[4][2];
    #pragma unroll
    for (int mt = 0; mt < 4; ++mt)
        #pragma unroll
        for (int sl = 0; sl < 2; ++sl) {
            s_acc[mt][sl][0] = 0.f; s_acc[mt][sl][1] = 0.f;
            s_acc[mt][sl][2] = 0.f; s_acc[mt][sl][3] = 0.f;
        }

    __bf16* Tw = Tw_all + w * (64 * TW);   // this wave's private T region

    #pragma unroll 1
    for (int cch = 0; cch < 2; ++cch) {
        // ---- GEMM1: T_w[:, 0..32) = A @ M'[:, c*128+w*32 ..+32) + r' ----
        f32x4 acc[4][2];
        #pragma unroll
        for (int nt = 0; nt < 2; ++nt) {
            const float rb = rv[cch * 128 + w * 32 + nt * 16 + l15];
            #pragma unroll
            for (int mt = 0; mt < 4; ++mt) {
                acc[mt][nt][0] = rb; acc[mt][nt][1] = rb;
                acc[mt][nt][2] = rb; acc[mt][nt][3] = rb;
            }
        }
        #pragma unroll
        for (int kt = 0; kt < 8; ++kt) {
            bf16x8 afr[4];
            #pragma unroll
            for (int mt = 0; mt < 4; ++mt)
                afr[mt] = *(const bf16x8*)(&hs_s[(mt * 16 + l15) * STRB + kt * 32 + quad * 8]);
            bf16x8 bfr[2];
            #pragma unroll
            for (int nt = 0; nt < 2; ++nt)
                bfr[nt] = *(const bf16x8*)(Mb +
                    ((size_t)(kt * 16 + cch * 8 + w * 2 + nt) * 64 + lane) * 8);
            #pragma unroll
            for (int mt = 0; mt < 4; ++mt)
                #pragma unroll
                for (int nt = 0; nt < 2; ++nt)
                    acc[mt][nt] = __builtin_amdgcn_mfma_f32_16x16x32_bf16(
                        afr[mt], bfr[nt], acc[mt][nt], 0, 0, 0);
        }
        // T -> PRIVATE LDS bf16 (row = mt*16+quad*4+r, col local 0..31).
        // Same-wave write->read: per-wave in-order LDS pipe, no barrier.
        #pragma unroll
        for (int mt = 0; mt < 4; ++mt)
            #pragma unroll
            for (int nt = 0; nt < 2; ++nt)
                #pragma unroll
                for (int r = 0; r < 4; ++r)
                    Tw[(mt * 16 + quad * 4 + r) * TW + nt * 16 + l15] =
                        (__bf16)acc[mt][nt][r];

        // ---- GEMM2 band partial: S += T_w @ (A[:, slice])^T ----
        bf16x8 brow[4];
        #pragma unroll
        for (int nt = 0; nt < 4; ++nt)
            brow[nt] = *(const bf16x8*)(
                &hs_s[(nt * 16 + l15) * STRB + cch * 128 + w * 32 + quad * 8]);
        #pragma unroll
        for (int mt = 0; mt < 4; ++mt) {
            const bf16x8 afr2 = *(const bf16x8*)(&Tw[(mt * 16 + l15) * TW + quad * 8]);
            s_acc[mt][0] = __builtin_amdgcn_mfma_f32_16x16x32_bf16(
                afr2, brow[mt], s_acc[mt][0], 0, 0, 0);
            s_acc[mt][1] = __builtin_amdgcn_mfma_f32_16x16x32_bf16(
                afr2, brow[(mt + 1) & 3], s_acc[mt][1], 0, 0, 0);
        }
    }
    __syncthreads();   // all waves' GEMM2 done; T regions dead -> reuse as S0/S1

    // ---- cross-wave reduce: waves 0/2 store to S0/S1, waves 1/3 add ----
    {
        float* Sbuf = (w & 2) ? S1 : S0;
        if (!(w & 1)) {
            #pragma unroll
            for (int mt = 0; mt < 4; ++mt)
                #pragma unroll
                for (int sl = 0; sl < 2; ++sl)
                    #pragma unroll
                    for (int r = 0; r < 4; ++r)
                        Sbuf[(mt * 16 + quad * 4 + r) * 36 + sl * 16 + l15] =
                            s_acc[mt][sl][r];
        }
        __syncthreads();
        if (w & 1) {
            #pragma unroll
            for (int mt = 0; mt < 4; ++mt)
                #pragma unroll
                for (int sl = 0; sl < 2; ++sl)
                    #pragma unroll
                    for (int r = 0; r < 4; ++r)
                        Sbuf[(mt * 16 + quad * 4 + r) * 36 + sl * 16 + l15] +=
                            s_acc[mt][sl][r];
        }
        __syncthreads();
        #pragma unroll
        for (int k2 = 0; k2 < 9; ++k2)
            S0[k2 * 256 + tid] += S1[k2 * 256 + tid];   // 2304 = 9*256
        __syncthreads();
    }

    // ---- per-edge logits + group-of-16 softmax ----
    const int e0  = tid * 4;
    const int be0 = b * Ev + e0;
    int srcs[4], dsts[4];
    #pragma unroll
    for (int j = 0; j < 4; ++j) {
        srcs[j] = eidx[be0 + j];
        dsts[j] = eidx[BE + be0 + j];
    }
    float lg[4];
    #pragma unroll
    for (int j = 0; j < 4; ++j) {
        // dst in {src+1..src+16} mod 64 -> slot in {0,1} always
        const int slot = ((dsts[j] >> 4) - (srcs[j] >> 4)) & 3;
        lg[j] = S0[srcs[j] * 36 + slot * 16 + (dsts[j] & 15)];
    }

    float mx = fmaxf(fmaxf(lg[0], lg[1]), fmaxf(lg[2], lg[3]));
    mx = fmaxf(mx, __shfl_xor(mx, 1));
    mx = fmaxf(mx, __shfl_xor(mx, 2));
    float ex[4], sm = 0.f;
    #pragma unroll
    for (int j = 0; j < 4; ++j) { ex[j] = __expf(lg[j] - mx); sm += ex[j]; }
    sm += __shfl_xor(sm, 1);
    sm += __shfl_xor(sm, 2);
    const float inv = 1.0f / sm;

    if (USE_WS) {
        float4 o = make_float4(ex[0] * inv, ex[1] * inv, ex[2] * inv, ex[3] * inv);
        *(float4*)(probs_or_out + (size_t)bl * 1024 + e0) = o;
    } else {
        const float skip = skipp[0];
        const float om = 1.0f - skip;
        #pragma unroll
        for (int j = 0; j < 4; ++j) {
            float g = fmaf(skip, ew[be0 + j], om * (ex[j] * inv));
            probs_or_out[(size_t)(be0 + j) * Lv + l] = g;
        }
    }
}

// ---------------------------------------------------------------------------
// Output kernel: tiled transpose of probs (b,l,e) -> ew_out (be,l), plus ei
// broadcast. Block = (lt, et, b) transposes one 64x64 tile.
// ---------------------------------------------------------------------------
__global__ __launch_bounds__(256) void output_kernel(
    const float* __restrict__ probs, const int* __restrict__ eidx,
    const float* __restrict__ ew, const float* __restrict__ skipp,
    float* __restrict__ out)
{
    __shared__ float tile[64 * 68];
    const int lt = blockIdx.x;   // 0..15
    const int et = blockIdx.y;   // 0..15
    const int b  = blockIdx.z;   // 0..3
    const int t  = threadIdx.x;
    const int tr = t >> 4;       // 0..15
    const int tc = t & 15;       // 0..15

    #pragma unroll
    for (int q = 0; q < 4; ++q) {
        const int lloc = q * 16 + tr;
        float4 v = *(const float4*)(probs +
            ((size_t)(b * 1024 + lt * 64 + lloc)) * 1024 + et * 64 + tc * 4);
        *(float4*)(&tile[lloc * 68 + tc * 4]) = v;
    }
    __syncthreads();

    const float skip = skipp[0];
    const float om = 1.0f - skip;
    float* out_ei0 = out;
    float* out_ei1 = out + EI_PLANE;
    float* out_ew  = out + 2 * EI_PLANE;

    #pragma unroll
    for (int q = 0; q < 4; ++q) {
        const int eloc = q * 16 + tr;
        const int be = b * Ev + et * 64 + eloc;
        const float w  = ew[be];
        const float sv = (float)eidx[be];
        const float dv = (float)eidx[BE + be];
        const int lloc0 = tc * 4;
        float4 o;
        o.x = fmaf(skip, w, om * tile[(lloc0 + 0) * 68 + eloc]);
        o.y = fmaf(skip, w, om * tile[(lloc0 + 1) * 68 + eloc]);
        o.z = fmaf(skip, w, om * tile[(lloc0 + 2) * 68 + eloc]);
        o.w = fmaf(skip, w, om * tile[(lloc0 + 3) * 68 + eloc]);
        const size_t off = (size_t)be * Lv + lt * 64 + lloc0;
        *(float4*)(out_ew  + off) = o;
        *(float4*)(out_ei0 + off) = make_float4(sv, sv, sv, sv);
        *(float4*)(out_ei1 + off) = make_float4(dv, dv, dv, dv);
    }
}

// Fallback ei broadcast kernel (only used if ws too small for probs buffer)
__global__ __launch_bounds__(256) void ei_kernel(
    const int* __restrict__ eidx, float* __restrict__ out)
{
    const int blk = blockIdx.x;            // 0..8191  (c*4096 + j)
    const int c = blk >> 12;
    const int j = blk & 4095;
    const float v = (float)eidx[c * BE + j];
    float4 o = make_float4(v, v, v, v);
    *(float4*)(out + (size_t)blk * 1024 + threadIdx.x * 4) = o;
}

// ---------------------------------------------------------------------------
extern "C" void kernel_launch(void* const* d_in, const int* in_sizes, int n_in,
                              void* d_out, int out_size, void* d_ws, size_t ws_size,
                              hipStream_t stream)
{
    const float* hs   = (const float*)d_in[0];
    const int*   eidx = (const int*)d_in[1];
    const float* ew   = (const float*)d_in[2];
    const float* Wq   = (const float*)d_in[3];
    const float* bq   = (const float*)d_in[4];
    const float* Wk   = (const float*)d_in[5];
    // d_in[6] = bk: provably unused (cancels in softmax)
    const float* skip = (const float*)d_in[7];

    char* wsb = (char*)d_ws;
    __bf16* Mb   = (__bf16*)wsb;                       // 65536 bf16 = 128 KiB
    float*  rv   = (float*)(wsb + 131072);             // 256 fp32 = 1 KiB
    float*  probs = (float*)(wsb + 132096);            // 4M fp32 = 16 MiB
    const size_t need = 132096 + (size_t)Bv * Lv * Ev * sizeof(float);

    precompute_kernel<<<dim3(257), dim3(256), 0, stream>>>(Wq, Wk, bq, Mb, rv);

    if (ws_size >= need) {
        edge_main<true><<<dim3(Bv * Lv), dim3(256), 0, stream>>>(
            hs, eidx, ew, skip, Mb, rv, probs);
        output_kernel<<<dim3(16, 16, 4), dim3(256), 0, stream>>>(
            probs, eidx, ew, skip, (float*)d_out);
    } else {
        float* out_ew = (float*)d_out + 2 * EI_PLANE;
        edge_main<false><<<dim3(Bv * Lv), dim3(256), 0, stream>>>(
            hs, eidx, ew, skip, Mb, rv, out_ew);
        ei_kernel<<<dim3(2 * BE), dim3(256), 0, stream>>>(eidx, (float*)d_out);
    }
}

// Round 3
// 434.980 us; speedup vs baseline: 1.2428x; 1.2428x over previous
//
#include <hip/hip_runtime.h>
#include <cstdint>
#include <cstddef>

// Problem constants (B=4, V=64, E=1024, L=1024, D=256, DEG=16)
constexpr int Bv = 4;
constexpr int Ev = 1024;      // edges per batch
constexpr int Lv = 1024;
constexpr int BE = Bv * Ev;   // 4096
constexpr size_t EI_PLANE = (size_t)BE * Lv;  // 4,194,304 elements per ei plane

// bf16 LDS row stride for hs tile: 256 + 8 pad -> 528 B rows (16B aligned;
// b128 fragment reads land 2-way on banks = free)
constexpr int STRB = 264;

typedef __bf16 bf16x8 __attribute__((ext_vector_type(8)));
typedef __bf16 bf16x4 __attribute__((ext_vector_type(4)));
typedef __bf16 bf16x2 __attribute__((ext_vector_type(2)));
typedef float  f32x4  __attribute__((ext_vector_type(4)));

// pack two f32 -> one dword of 2 bf16 (RNE, compiler emits v_cvt_pk_bf16_f32)
static __device__ __forceinline__ unsigned int pack_bf2(float lo, float hi) {
    union { bf16x2 h; unsigned int u; } c;
    c.h[0] = (__bf16)lo; c.h[1] = (__bf16)hi;
    return c.u;
}

// ---------------------------------------------------------------------------
// Precompute (grid 257 x 256 threads):
//  blocks 0..255: tile (i = blk>>4, j = blk&15) of M' = (Wq^T Wk) / 16,
//    bf16, written pre-swizzled to MFMA fragment layout (A- and B-fragment
//    layouts are identical for 16x16x32):
//      for element (d, t):  f = (d>>5)*16 + (t>>4);
//                           lane = ((d>>3)&3)*16 + (t&15); jj = d&7;
//      Mb[(f*64 + lane)*8 + jj] = M'[d][t]
//  block 256: rv[t] = (sum_i bq[i] * Wk[i*256+t]) / 16  (fp32)
//  (bk and the h_src-only bias terms cancel in the softmax -> never computed;
//   the 1/sqrt(D)=1/16 logit scale is folded in here.)
// ---------------------------------------------------------------------------
__global__ __launch_bounds__(256) void precompute_kernel(
    const float* __restrict__ Wq, const float* __restrict__ Wk,
    const float* __restrict__ bq, __bf16* __restrict__ Mb, float* __restrict__ rv)
{
    const int blk = blockIdx.x;
    const int tid = threadIdx.x;
    if (blk < 256) {
        __shared__ float qs[256 * 17];
        __shared__ float ks[256 * 17];
        const int i16 = (blk >> 4) * 16;   // d-tile base
        const int j16 = (blk & 15) * 16;   // t-tile base
        const int c  = tid & 15;
        const int r0 = tid >> 4;
        #pragma unroll
        for (int it = 0; it < 16; ++it) {
            const int r = it * 16 + r0;
            qs[r * 17 + c] = Wq[r * 256 + i16 + c];
            ks[r * 17 + c] = Wk[r * 256 + j16 + c];
        }
        __syncthreads();
        const int dd = tid >> 4;   // 0..15 local d
        const int tt = tid & 15;   // 0..15 local t
        float a0 = 0.f, a1 = 0.f, a2 = 0.f, a3 = 0.f;
        for (int r = 0; r < 256; r += 4) {
            a0 = fmaf(qs[(r + 0) * 17 + dd], ks[(r + 0) * 17 + tt], a0);
            a1 = fmaf(qs[(r + 1) * 17 + dd], ks[(r + 1) * 17 + tt], a1);
            a2 = fmaf(qs[(r + 2) * 17 + dd], ks[(r + 2) * 17 + tt], a2);
            a3 = fmaf(qs[(r + 3) * 17 + dd], ks[(r + 3) * 17 + tt], a3);
        }
        const float m = ((a0 + a1) + (a2 + a3)) * 0.0625f;
        const int d = i16 + dd, t = j16 + tt;
        const int f    = (d >> 5) * 16 + (t >> 4);
        const int lane = ((d >> 3) & 3) * 16 + (t & 15);
        const int jj   = d & 7;
        Mb[((size_t)f * 64 + lane) * 8 + jj] = (__bf16)m;
    } else {
        __shared__ float bqs[256];
        bqs[tid] = bq[tid];
        __syncthreads();
        float a0 = 0.f, a1 = 0.f;
        for (int i = 0; i < 256; i += 2) {
            a0 = fmaf(bqs[i + 0], Wk[(i + 0) * 256 + tid], a0);
            a1 = fmaf(bqs[i + 1], Wk[(i + 1) * 256 + tid], a1);
        }
        rv[tid] = (a0 + a1) * 0.0625f;
    }
}

// ---------------------------------------------------------------------------
// Main fused kernel, register-resident T (no T-LDS roundtrip, no spills).
// One block (4 waves) per (b,l). LDS = hs tile only (33792 B) -> 4 blocks/CU.
//  1) stage A = hs[b,:,l,:] (64x256) as bf16 in LDS (16B stores); barrier.
//  2) per wave, barrier-free, for chunk c in {0,1} (t-slice c*128+w*32 ..+32):
//     GEMM1 SWAPPED: Tt = M'[:, slice]^T-frag (A-op) x A-frag (B-op)
//       -> acc[tt][mt]: lane holds col v = l15, rows t = quad*4+r  (64 MFMA)
//     pack f32->bf16 pairs (cvt_pk) + permlane32/16_swap pairs to route
//       per-lane T values into GEMM2's A-fragment IN REGISTERS
//     GEMM2 band partial: S += T @ A[:, slice]^T, BAND-ONLY n-tiles
//       {mt, (mt+1)&3} (edge struct: dst in src+1..src+16 mod 64): 8 MFMA
//  3) barrier; reduce 4 partial band-S via LDS overlaid on hs_s.
//  4) per-edge logits + group-of-16 softmax via shfl; write probs
//     (or scattered ew_out directly if !USE_WS)
// ---------------------------------------------------------------------------
template <bool USE_WS>
__global__ __launch_bounds__(256) void edge_main(
    const float* __restrict__ hs, const int* __restrict__ eidx,
    const float* __restrict__ ew, const float* __restrict__ skipp,
    const __bf16* __restrict__ Mb, const float* __restrict__ rv,
    float* __restrict__ probs_or_out)
{
    __shared__ __bf16 hs_s[64 * STRB];          // 33792 B (only LDS block)
    float* S0 = (float*)hs_s;                   // band-S 64 x 36 f32 (9216 B)
    float* S1 = S0 + 2304;                      // second partial (9216 B)
    // (S0/S1 overlay hs_s -- only written after the post-GEMM2 barrier)

    const int bl = blockIdx.x;          // 0..4095
    const int b  = bl >> 10;
    const int l  = bl & 1023;
    const int tid  = threadIdx.x;
    const int w    = tid >> 6;          // wave 0..3
    const int lane = tid & 63;
    const int l15  = lane & 15;
    const int quad = lane >> 4;

    // ---- stage hs tile (64 rows x 256 cols fp32 -> bf16), coalesced ----
    // Each lane owns 8 consecutive floats of one row -> one 16B LDS store.
    {
        const float* base = hs + ((size_t)b * 64 * 1024 + (size_t)l) * 256;
        const int half = lane >> 5;          // 0..1
        const int c8   = (lane & 31) * 8;    // col base
        #pragma unroll
        for (int k = 0; k < 8; ++k) {
            const int v = k * 8 + w * 2 + half;
            const float* p = base + (size_t)v * (1024 * 256) + c8;
            float4 va = *(const float4*)p;
            float4 vb = *(const float4*)(p + 4);
            bf16x8 h;
            h[0] = (__bf16)va.x; h[1] = (__bf16)va.y;
            h[2] = (__bf16)va.z; h[3] = (__bf16)va.w;
            h[4] = (__bf16)vb.x; h[5] = (__bf16)vb.y;
            h[6] = (__bf16)vb.z; h[7] = (__bf16)vb.w;
            *(bf16x8*)(&hs_s[v * STRB + c8]) = h;
        }
    }
    __syncthreads();

    // band-S accumulators: s_acc[mt][slot]; slot 0 -> n-tile mt, 1 -> (mt+1)&3
    f32x4 s_acc[4][2];
    #pragma unroll
    for (int mt = 0; mt < 4; ++mt)
        #pragma unroll
        for (int sl = 0; sl < 2; ++sl) {
            s_acc[mt][sl][0] = 0.f; s_acc[mt][sl][1] = 0.f;
            s_acc[mt][sl][2] = 0.f; s_acc[mt][sl][3] = 0.f;
        }

    #pragma unroll 1
    for (int cch = 0; cch < 2; ++cch) {
        // ---- GEMM1 (swapped): acc[tt][mt] = Tt tile, rows t, cols v ----
        // bias rv[t] is per-ROW of Tt: element r gets rv[..+quad*4+r]
        f32x4 acc[2][4];
        #pragma unroll
        for (int tt = 0; tt < 2; ++tt) {
            const f32x4 rb = *(const f32x4*)(rv + cch * 128 + w * 32 + tt * 16 + quad * 4);
            #pragma unroll
            for (int mt = 0; mt < 4; ++mt)
                acc[tt][mt] = rb;
        }
        #pragma unroll
        for (int kt = 0; kt < 8; ++kt) {
            bf16x8 mfr[2];   // M' fragments (A-operand), rows t
            #pragma unroll
            for (int tt = 0; tt < 2; ++tt)
                mfr[tt] = *(const bf16x8*)(Mb +
                    ((size_t)(kt * 16 + cch * 8 + w * 2 + tt) * 64 + lane) * 8);
            bf16x8 hfr[4];   // hs fragments (B-operand), cols v
            #pragma unroll
            for (int mt = 0; mt < 4; ++mt)
                hfr[mt] = *(const bf16x8*)(&hs_s[(mt * 16 + l15) * STRB + kt * 32 + quad * 8]);
            #pragma unroll
            for (int tt = 0; tt < 2; ++tt)
                #pragma unroll
                for (int mt = 0; mt < 4; ++mt)
                    acc[tt][mt] = __builtin_amdgcn_mfma_f32_16x16x32_bf16(
                        mfr[tt], hfr[mt], acc[tt][mt], 0, 0, 0);
        }

        // ---- pack + permlane route -> GEMM2 A-frags; band partial S ----
        bf16x8 brow[4];
        #pragma unroll
        for (int nt = 0; nt < 4; ++nt)
            brow[nt] = *(const bf16x8*)(
                &hs_s[(nt * 16 + l15) * STRB + cch * 128 + w * 32 + quad * 8]);
        #pragma unroll
        for (int mt = 0; mt < 4; ++mt) {
            // per lane (v = l15, group g = quad): dwords of T[v][t-pairs]
            unsigned int Ar = pack_bf2(acc[0][mt][0], acc[0][mt][1]); // t=g*4+{0,1}
            unsigned int Br = pack_bf2(acc[0][mt][2], acc[0][mt][3]); // t=g*4+{2,3}
            unsigned int Cr = pack_bf2(acc[1][mt][0], acc[1][mt][1]); // t=16+g*4+{0,1}
            unsigned int Dr = pack_bf2(acc[1][mt][2], acc[1][mt][3]); // t=16+g*4+{2,3}
            // route to A-frag: dest quad q needs dwords 4q..4q+3 (k = quad*8+j)
            asm("v_permlane32_swap_b32 %0, %1" : "+v"(Ar), "+v"(Cr));
            asm("v_permlane16_swap_b32 %0, %1" : "+v"(Ar), "+v"(Cr));
            asm("v_permlane32_swap_b32 %0, %1" : "+v"(Br), "+v"(Dr));
            asm("v_permlane16_swap_b32 %0, %1" : "+v"(Br), "+v"(Dr));
            union { uint4 u; bf16x8 h; } fr;
            fr.u = make_uint4(Ar, Br, Cr, Dr);   // slots 0..3 = F0,F1,F2,F3
            s_acc[mt][0] = __builtin_amdgcn_mfma_f32_16x16x32_bf16(
                fr.h, brow[mt], s_acc[mt][0], 0, 0, 0);
            s_acc[mt][1] = __builtin_amdgcn_mfma_f32_16x16x32_bf16(
                fr.h, brow[(mt + 1) & 3], s_acc[mt][1], 0, 0, 0);
        }
    }
    __syncthreads();   // all waves done with hs_s -> reuse as S0/S1

    // ---- cross-wave reduce: waves 0/2 store to S0/S1, waves 1/3 add ----
    {
        float* Sbuf = (w & 2) ? S1 : S0;
        if (!(w & 1)) {
            #pragma unroll
            for (int mt = 0; mt < 4; ++mt)
                #pragma unroll
                for (int sl = 0; sl < 2; ++sl)
                    #pragma unroll
                    for (int r = 0; r < 4; ++r)
                        Sbuf[(mt * 16 + quad * 4 + r) * 36 + sl * 16 + l15] =
                            s_acc[mt][sl][r];
        }
        __syncthreads();
        if (w & 1) {
            #pragma unroll
            for (int mt = 0; mt < 4; ++mt)
                #pragma unroll
                for (int sl = 0; sl < 2; ++sl)
                    #pragma unroll
                    for (int r = 0; r < 4; ++r)
                        Sbuf[(mt * 16 + quad * 4 + r) * 36 + sl * 16 + l15] +=
                            s_acc[mt][sl][r];
        }
        __syncthreads();
        #pragma unroll
        for (int k2 = 0; k2 < 9; ++k2)
            S0[k2 * 256 + tid] += S1[k2 * 256 + tid];   // 2304 = 9*256
        __syncthreads();
    }

    // ---- per-edge logits + group-of-16 softmax ----
    const int e0  = tid * 4;
    const int be0 = b * Ev + e0;
    int srcs[4], dsts[4];
    #pragma unroll
    for (int j = 0; j < 4; ++j) {
        srcs[j] = eidx[be0 + j];
        dsts[j] = eidx[BE + be0 + j];
    }
    float lg[4];
    #pragma unroll
    for (int j = 0; j < 4; ++j) {
        // dst in {src+1..src+16} mod 64 -> slot in {0,1} always
        const int slot = ((dsts[j] >> 4) - (srcs[j] >> 4)) & 3;
        lg[j] = S0[srcs[j] * 36 + slot * 16 + (dsts[j] & 15)];
    }

    float mx = fmaxf(fmaxf(lg[0], lg[1]), fmaxf(lg[2], lg[3]));
    mx = fmaxf(mx, __shfl_xor(mx, 1));
    mx = fmaxf(mx, __shfl_xor(mx, 2));
    float ex[4], sm = 0.f;
    #pragma unroll
    for (int j = 0; j < 4; ++j) { ex[j] = __expf(lg[j] - mx); sm += ex[j]; }
    sm += __shfl_xor(sm, 1);
    sm += __shfl_xor(sm, 2);
    const float inv = 1.0f / sm;

    if (USE_WS) {
        float4 o = make_float4(ex[0] * inv, ex[1] * inv, ex[2] * inv, ex[3] * inv);
        *(float4*)(probs_or_out + (size_t)bl * 1024 + e0) = o;
    } else {
        const float skip = skipp[0];
        const float om = 1.0f - skip;
        #pragma unroll
        for (int j = 0; j < 4; ++j) {
            float g = fmaf(skip, ew[be0 + j], om * (ex[j] * inv));
            probs_or_out[(size_t)(be0 + j) * Lv + l] = g;
        }
    }
}

// ---------------------------------------------------------------------------
// Output kernel: tiled transpose of probs (b,l,e) -> ew_out (be,l), plus ei
// broadcast. Block = (lt, et, b) transposes one 64x64 tile.
// ---------------------------------------------------------------------------
__global__ __launch_bounds__(256) void output_kernel(
    const float* __restrict__ probs, const int* __restrict__ eidx,
    const float* __restrict__ ew, const float* __restrict__ skipp,
    float* __restrict__ out)
{
    __shared__ float tile[64 * 68];
    const int lt = blockIdx.x;   // 0..15
    const int et = blockIdx.y;   // 0..15
    const int b  = blockIdx.z;   // 0..3
    const int t  = threadIdx.x;
    const int tr = t >> 4;       // 0..15
    const int tc = t & 15;       // 0..15

    #pragma unroll
    for (int q = 0; q < 4; ++q) {
        const int lloc = q * 16 + tr;
        float4 v = *(const float4*)(probs +
            ((size_t)(b * 1024 + lt * 64 + lloc)) * 1024 + et * 64 + tc * 4);
        *(float4*)(&tile[lloc * 68 + tc * 4]) = v;
    }
    __syncthreads();

    const float skip = skipp[0];
    const float om = 1.0f - skip;
    float* out_ei0 = out;
    float* out_ei1 = out + EI_PLANE;
    float* out_ew  = out + 2 * EI_PLANE;

    #pragma unroll
    for (int q = 0; q < 4; ++q) {
        const int eloc = q * 16 + tr;
        const int be = b * Ev + et * 64 + eloc;
        const float w  = ew[be];
        const float sv = (float)eidx[be];
        const float dv = (float)eidx[BE + be];
        const int lloc0 = tc * 4;
        float4 o;
        o.x = fmaf(skip, w, om * tile[(lloc0 + 0) * 68 + eloc]);
        o.y = fmaf(skip, w, om * tile[(lloc0 + 1) * 68 + eloc]);
        o.z = fmaf(skip, w, om * tile[(lloc0 + 2) * 68 + eloc]);
        o.w = fmaf(skip, w, om * tile[(lloc0 + 3) * 68 + eloc]);
        const size_t off = (size_t)be * Lv + lt * 64 + lloc0;
        *(float4*)(out_ew  + off) = o;
        *(float4*)(out_ei0 + off) = make_float4(sv, sv, sv, sv);
        *(float4*)(out_ei1 + off) = make_float4(dv, dv, dv, dv);
    }
}

// Fallback ei broadcast kernel (only used if ws too small for probs buffer)
__global__ __launch_bounds__(256) void ei_kernel(
    const int* __restrict__ eidx, float* __restrict__ out)
{
    const int blk = blockIdx.x;            // 0..8191  (c*4096 + j)
    const int c = blk >> 12;
    const int j = blk & 4095;
    const float v = (float)eidx[c * BE + j];
    float4 o = make_float4(v, v, v, v);
    *(float4*)(out + (size_t)blk * 1024 + threadIdx.x * 4) = o;
}

// ---------------------------------------------------------------------------
extern "C" void kernel_launch(void* const* d_in, const int* in_sizes, int n_in,
                              void* d_out, int out_size, void* d_ws, size_t ws_size,
                              hipStream_t stream)
{
    const float* hs   = (const float*)d_in[0];
    const int*   eidx = (const int*)d_in[1];
    const float* ew   = (const float*)d_in[2];
    const float* Wq   = (const float*)d_in[3];
    const float* bq   = (const float*)d_in[4];
    const float* Wk   = (const float*)d_in[5];
    // d_in[6] = bk: provably unused (cancels in softmax)
    const float* skip = (const float*)d_in[7];

    char* wsb = (char*)d_ws;
    __bf16* Mb   = (__bf16*)wsb;                       // 65536 bf16 = 128 KiB
    float*  rv   = (float*)(wsb + 131072);             // 256 fp32 = 1 KiB
    float*  probs = (float*)(wsb + 132096);            // 4M fp32 = 16 MiB
    const size_t need = 132096 + (size_t)Bv * Lv * Ev * sizeof(float);

    precompute_kernel<<<dim3(257), dim3(256), 0, stream>>>(Wq, Wk, bq, Mb, rv);

    if (ws_size >= need) {
        edge_main<true><<<dim3(Bv * Lv), dim3(256), 0, stream>>>(
            hs, eidx, ew, skip, Mb, rv, probs);
        output_kernel<<<dim3(16, 16, 4), dim3(256), 0, stream>>>(
            probs, eidx, ew, skip, (float*)d_out);
    } else {
        float* out_ew = (float*)d_out + 2 * EI_PLANE;
        edge_main<false><<<dim3(Bv * Lv), dim3(256), 0, stream>>>(
            hs, eidx, ew, skip, Mb, rv, out_ew);
        ei_kernel<<<dim3(2 * BE), dim3(256), 0, stream>>>(eidx, (float*)d_out);
    }
}

// Round 4
// 433.879 us; speedup vs baseline: 1.2459x; 1.0025x over previous
//
#include <hip/hip_runtime.h>
#include <cstdint>
#include <cstddef>

// Problem constants (B=4, V=64, E=1024, L=1024, D=256, DEG=16)
constexpr int Bv = 4;
constexpr int Ev = 1024;      // edges per batch
constexpr int Lv = 1024;
constexpr int BE = Bv * Ev;   // 4096
constexpr size_t EI_PLANE = (size_t)BE * Lv;  // 4,194,304 elements per ei plane

// bf16 LDS row stride for hs tile: 256 + 8 pad -> 528 B rows (16B aligned;
// b128 fragment reads land 2-way on banks = free)
constexpr int STRB = 264;

typedef __bf16 bf16x8 __attribute__((ext_vector_type(8)));
typedef __bf16 bf16x4 __attribute__((ext_vector_type(4)));
typedef __bf16 bf16x2 __attribute__((ext_vector_type(2)));
typedef float  f32x4  __attribute__((ext_vector_type(4)));

// pack two f32 -> one dword of 2 bf16 (RNE, compiler emits v_cvt_pk_bf16_f32)
static __device__ __forceinline__ unsigned int pack_bf2(float lo, float hi) {
    union { bf16x2 h; unsigned int u; } c;
    c.h[0] = (__bf16)lo; c.h[1] = (__bf16)hi;
    return c.u;
}

// ---------------------------------------------------------------------------
// Precompute (grid 257 x 256 threads):
//  blocks 0..255: tile (i = blk>>4, j = blk&15) of M' = (Wq^T Wk) / 16,
//    bf16, written pre-swizzled to MFMA fragment layout (A- and B-fragment
//    layouts are identical for 16x16x32):
//      for element (d, t):  f = (d>>5)*16 + (t>>4);
//                           lane = ((d>>3)&3)*16 + (t&15); jj = d&7;
//      Mb[(f*64 + lane)*8 + jj] = M'[d][t]
//  block 256: rv[t] = (sum_i bq[i] * Wk[i*256+t]) / 16  (fp32)
//  (bk and the h_src-only bias terms cancel in the softmax -> never computed;
//   the 1/sqrt(D)=1/16 logit scale is folded in here.)
// ---------------------------------------------------------------------------
__global__ __launch_bounds__(256) void precompute_kernel(
    const float* __restrict__ Wq, const float* __restrict__ Wk,
    const float* __restrict__ bq, __bf16* __restrict__ Mb, float* __restrict__ rv)
{
    const int blk = blockIdx.x;
    const int tid = threadIdx.x;
    if (blk < 256) {
        __shared__ float qs[256 * 17];
        __shared__ float ks[256 * 17];
        const int i16 = (blk >> 4) * 16;   // d-tile base
        const int j16 = (blk & 15) * 16;   // t-tile base
        const int c  = tid & 15;
        const int r0 = tid >> 4;
        #pragma unroll
        for (int it = 0; it < 16; ++it) {
            const int r = it * 16 + r0;
            qs[r * 17 + c] = Wq[r * 256 + i16 + c];
            ks[r * 17 + c] = Wk[r * 256 + j16 + c];
        }
        __syncthreads();
        const int dd = tid >> 4;   // 0..15 local d
        const int tt = tid & 15;   // 0..15 local t
        float a0 = 0.f, a1 = 0.f, a2 = 0.f, a3 = 0.f;
        for (int r = 0; r < 256; r += 4) {
            a0 = fmaf(qs[(r + 0) * 17 + dd], ks[(r + 0) * 17 + tt], a0);
            a1 = fmaf(qs[(r + 1) * 17 + dd], ks[(r + 1) * 17 + tt], a1);
            a2 = fmaf(qs[(r + 2) * 17 + dd], ks[(r + 2) * 17 + tt], a2);
            a3 = fmaf(qs[(r + 3) * 17 + dd], ks[(r + 3) * 17 + tt], a3);
        }
        const float m = ((a0 + a1) + (a2 + a3)) * 0.0625f;
        const int d = i16 + dd, t = j16 + tt;
        const int f    = (d >> 5) * 16 + (t >> 4);
        const int lane = ((d >> 3) & 3) * 16 + (t & 15);
        const int jj   = d & 7;
        Mb[((size_t)f * 64 + lane) * 8 + jj] = (__bf16)m;
    } else {
        __shared__ float bqs[256];
        bqs[tid] = bq[tid];
        __syncthreads();
        float a0 = 0.f, a1 = 0.f;
        for (int i = 0; i < 256; i += 2) {
            a0 = fmaf(bqs[i + 0], Wk[(i + 0) * 256 + tid], a0);
            a1 = fmaf(bqs[i + 1], Wk[(i + 1) * 256 + tid], a1);
        }
        rv[tid] = (a0 + a1) * 0.0625f;
    }
}

// ---------------------------------------------------------------------------
// Main fused kernel, register-resident T, VGPR-dieted for 4 waves/SIMD.
// One block (4 waves) per (b,l). LDS = hs tile only (33792 B) -> 4 blocks/CU
// if VGPR <= 128 (the point of the mt-group split below).
//  1) stage A = hs[b,:,l,:] (64x256) as bf16 in LDS (16B stores); barrier.
//  2) per wave, barrier-free; for chunk c in {0,1} (t-slice c*128+w*32 ..+32),
//     and mt-group mtg in {0,1} (m-tiles mtg*2, mtg*2+1):
//       GEMM1 SWAPPED: acc[tt][mi] = M'-frag (A-op) x hs-frag (B-op)
//         -> lane holds col v, rows t (32 MFMA per group; acc = 16 VGPR)
//       pack f32->bf16 (cvt_pk) + permlane32/16_swap -> GEMM2 A-frag in regs
//       GEMM2 band partial: S += T @ A[:, slice]^T, n-tiles {mt, (mt+1)&3}
//         (edge struct: dst in src+1..src+16 mod 64): 4 MFMA per group
//  3) barrier; reduce 4 partial band-S via LDS overlaid on hs_s.
//  4) per-edge logits + group-of-16 softmax via shfl; write probs
//     (or scattered ew_out directly if !USE_WS)
// ---------------------------------------------------------------------------
template <bool USE_WS>
__global__ __launch_bounds__(256) void edge_main(
    const float* __restrict__ hs, const int* __restrict__ eidx,
    const float* __restrict__ ew, const float* __restrict__ skipp,
    const __bf16* __restrict__ Mb, const float* __restrict__ rv,
    float* __restrict__ probs_or_out)
{
    __shared__ __bf16 hs_s[64 * STRB];          // 33792 B (only LDS block)
    float* S0 = (float*)hs_s;                   // band-S 64 x 36 f32 (9216 B)
    float* S1 = S0 + 2304;                      // second partial (9216 B)
    // (S0/S1 overlay hs_s -- only written after the post-GEMM2 barrier)

    const int bl = blockIdx.x;          // 0..4095
    const int b  = bl >> 10;
    const int l  = bl & 1023;
    const int tid  = threadIdx.x;
    const int w    = tid >> 6;          // wave 0..3
    const int lane = tid & 63;
    const int l15  = lane & 15;
    const int quad = lane >> 4;

    // ---- stage hs tile (64 rows x 256 cols fp32 -> bf16), coalesced ----
    // Each lane owns 8 consecutive floats of one row -> one 16B LDS store.
    {
        const float* base = hs + ((size_t)b * 64 * 1024 + (size_t)l) * 256;
        const int half = lane >> 5;          // 0..1
        const int c8   = (lane & 31) * 8;    // col base
        #pragma unroll
        for (int k = 0; k < 8; ++k) {
            const int v = k * 8 + w * 2 + half;
            const float* p = base + (size_t)v * (1024 * 256) + c8;
            float4 va = *(const float4*)p;
            float4 vb = *(const float4*)(p + 4);
            bf16x8 h;
            h[0] = (__bf16)va.x; h[1] = (__bf16)va.y;
            h[2] = (__bf16)va.z; h[3] = (__bf16)va.w;
            h[4] = (__bf16)vb.x; h[5] = (__bf16)vb.y;
            h[6] = (__bf16)vb.z; h[7] = (__bf16)vb.w;
            *(bf16x8*)(&hs_s[v * STRB + c8]) = h;
        }
    }
    __syncthreads();

    // band-S accumulators: s_acc[mt][slot]; slot 0 -> n-tile mt, 1 -> (mt+1)&3
    f32x4 s_acc[4][2];
    #pragma unroll
    for (int mt = 0; mt < 4; ++mt)
        #pragma unroll
        for (int sl = 0; sl < 2; ++sl) {
            s_acc[mt][sl][0] = 0.f; s_acc[mt][sl][1] = 0.f;
            s_acc[mt][sl][2] = 0.f; s_acc[mt][sl][3] = 0.f;
        }

    #pragma unroll 1
    for (int cch = 0; cch < 2; ++cch) {
        #pragma unroll
        for (int mtg = 0; mtg < 2; ++mtg) {
            // ---- GEMM1 (swapped), m-tiles {mtg*2, mtg*2+1} only ----
            // acc[tt][mi]: lane holds col v = mt*16+l15, rows t = quad*4+r.
            // bias rv[t] is per-ROW: element r gets rv[..+quad*4+r].
            f32x4 acc[2][2];
            #pragma unroll
            for (int tt = 0; tt < 2; ++tt) {
                const f32x4 rb = *(const f32x4*)(rv + cch * 128 + w * 32 + tt * 16 + quad * 4);
                acc[tt][0] = rb;
                acc[tt][1] = rb;
            }
            #pragma unroll
            for (int kt = 0; kt < 8; ++kt) {
                bf16x8 mfr[2];   // M' fragments (A-operand), rows t
                #pragma unroll
                for (int tt = 0; tt < 2; ++tt)
                    mfr[tt] = *(const bf16x8*)(Mb +
                        ((size_t)(kt * 16 + cch * 8 + w * 2 + tt) * 64 + lane) * 8);
                #pragma unroll
                for (int mi = 0; mi < 2; ++mi) {
                    const bf16x8 hfr = *(const bf16x8*)(
                        &hs_s[((mtg * 2 + mi) * 16 + l15) * STRB + kt * 32 + quad * 8]);
                    acc[0][mi] = __builtin_amdgcn_mfma_f32_16x16x32_bf16(
                        mfr[0], hfr, acc[0][mi], 0, 0, 0);
                    acc[1][mi] = __builtin_amdgcn_mfma_f32_16x16x32_bf16(
                        mfr[1], hfr, acc[1][mi], 0, 0, 0);
                }
            }
            // ---- pack + permlane route -> GEMM2 A-frags; band partial S ----
            #pragma unroll
            for (int mi = 0; mi < 2; ++mi) {
                const int mt = mtg * 2 + mi;
                unsigned int Ar = pack_bf2(acc[0][mi][0], acc[0][mi][1]); // t=g*4+{0,1}
                unsigned int Br = pack_bf2(acc[0][mi][2], acc[0][mi][3]); // t=g*4+{2,3}
                unsigned int Cr = pack_bf2(acc[1][mi][0], acc[1][mi][1]); // t=16+g*4+{0,1}
                unsigned int Dr = pack_bf2(acc[1][mi][2], acc[1][mi][3]); // t=16+g*4+{2,3}
                // route to A-frag: dest quad q needs dwords 4q..4q+3
                asm("v_permlane32_swap_b32 %0, %1" : "+v"(Ar), "+v"(Cr));
                asm("v_permlane16_swap_b32 %0, %1" : "+v"(Ar), "+v"(Cr));
                asm("v_permlane32_swap_b32 %0, %1" : "+v"(Br), "+v"(Dr));
                asm("v_permlane16_swap_b32 %0, %1" : "+v"(Br), "+v"(Dr));
                union { uint4 u; bf16x8 h; } fr;
                fr.u = make_uint4(Ar, Br, Cr, Dr);   // slots 0..3 = F0,F1,F2,F3
                const bf16x8 browa = *(const bf16x8*)(
                    &hs_s[(mt * 16 + l15) * STRB + cch * 128 + w * 32 + quad * 8]);
                const bf16x8 browb = *(const bf16x8*)(
                    &hs_s[(((mt + 1) & 3) * 16 + l15) * STRB + cch * 128 + w * 32 + quad * 8]);
                s_acc[mt][0] = __builtin_amdgcn_mfma_f32_16x16x32_bf16(
                    fr.h, browa, s_acc[mt][0], 0, 0, 0);
                s_acc[mt][1] = __builtin_amdgcn_mfma_f32_16x16x32_bf16(
                    fr.h, browb, s_acc[mt][1], 0, 0, 0);
            }
        }
    }
    __syncthreads();   // all waves done with hs_s -> reuse as S0/S1

    // ---- cross-wave reduce: waves 0/2 store to S0/S1, waves 1/3 add ----
    {
        float* Sbuf = (w & 2) ? S1 : S0;
        if (!(w & 1)) {
            #pragma unroll
            for (int mt = 0; mt < 4; ++mt)
                #pragma unroll
                for (int sl = 0; sl < 2; ++sl)
                    #pragma unroll
                    for (int r = 0; r < 4; ++r)
                        Sbuf[(mt * 16 + quad * 4 + r) * 36 + sl * 16 + l15] =
                            s_acc[mt][sl][r];
        }
        __syncthreads();
        if (w & 1) {
            #pragma unroll
            for (int mt = 0; mt < 4; ++mt)
                #pragma unroll
                for (int sl = 0; sl < 2; ++sl)
                    #pragma unroll
                    for (int r = 0; r < 4; ++r)
                        Sbuf[(mt * 16 + quad * 4 + r) * 36 + sl * 16 + l15] +=
                            s_acc[mt][sl][r];
        }
        __syncthreads();
        #pragma unroll
        for (int k2 = 0; k2 < 9; ++k2)
            S0[k2 * 256 + tid] += S1[k2 * 256 + tid];   // 2304 = 9*256
        __syncthreads();
    }

    // ---- per-edge logits + group-of-16 softmax ----
    const int e0  = tid * 4;
    const int be0 = b * Ev + e0;
    int srcs[4], dsts[4];
    #pragma unroll
    for (int j = 0; j < 4; ++j) {
        srcs[j] = eidx[be0 + j];
        dsts[j] = eidx[BE + be0 + j];
    }
    float lg[4];
    #pragma unroll
    for (int j = 0; j < 4; ++j) {
        // dst in {src+1..src+16} mod 64 -> slot in {0,1} always
        const int slot = ((dsts[j] >> 4) - (srcs[j] >> 4)) & 3;
        lg[j] = S0[srcs[j] * 36 + slot * 16 + (dsts[j] & 15)];
    }

    float mx = fmaxf(fmaxf(lg[0], lg[1]), fmaxf(lg[2], lg[3]));
    mx = fmaxf(mx, __shfl_xor(mx, 1));
    mx = fmaxf(mx, __shfl_xor(mx, 2));
    float ex[4], sm = 0.f;
    #pragma unroll
    for (int j = 0; j < 4; ++j) { ex[j] = __expf(lg[j] - mx); sm += ex[j]; }
    sm += __shfl_xor(sm, 1);
    sm += __shfl_xor(sm, 2);
    const float inv = 1.0f / sm;

    if (USE_WS) {
        float4 o = make_float4(ex[0] * inv, ex[1] * inv, ex[2] * inv, ex[3] * inv);
        *(float4*)(probs_or_out + (size_t)bl * 1024 + e0) = o;
    } else {
        const float skip = skipp[0];
        const float om = 1.0f - skip;
        #pragma unroll
        for (int j = 0; j < 4; ++j) {
            float g = fmaf(skip, ew[be0 + j], om * (ex[j] * inv));
            probs_or_out[(size_t)(be0 + j) * Lv + l] = g;
        }
    }
}

// ---------------------------------------------------------------------------
// Output kernel: tiled transpose of probs (b,l,e) -> ew_out (be,l), plus ei
// broadcast. Block = (lt, et, b) transposes one 64x64 tile.
// ---------------------------------------------------------------------------
__global__ __launch_bounds__(256) void output_kernel(
    const float* __restrict__ probs, const int* __restrict__ eidx,
    const float* __restrict__ ew, const float* __restrict__ skipp,
    float* __restrict__ out)
{
    __shared__ float tile[64 * 68];
    const int lt = blockIdx.x;   // 0..15
    const int et = blockIdx.y;   // 0..15
    const int b  = blockIdx.z;   // 0..3
    const int t  = threadIdx.x;
    const int tr = t >> 4;       // 0..15
    const int tc = t & 15;       // 0..15

    #pragma unroll
    for (int q = 0; q < 4; ++q) {
        const int lloc = q * 16 + tr;
        float4 v = *(const float4*)(probs +
            ((size_t)(b * 1024 + lt * 64 + lloc)) * 1024 + et * 64 + tc * 4);
        *(float4*)(&tile[lloc * 68 + tc * 4]) = v;
    }
    __syncthreads();

    const float skip = skipp[0];
    const float om = 1.0f - skip;
    float* out_ei0 = out;
    float* out_ei1 = out + EI_PLANE;
    float* out_ew  = out + 2 * EI_PLANE;

    #pragma unroll
    for (int q = 0; q < 4; ++q) {
        const int eloc = q * 16 + tr;
        const int be = b * Ev + et * 64 + eloc;
        const float w  = ew[be];
        const float sv = (float)eidx[be];
        const float dv = (float)eidx[BE + be];
        const int lloc0 = tc * 4;
        float4 o;
        o.x = fmaf(skip, w, om * tile[(lloc0 + 0) * 68 + eloc]);
        o.y = fmaf(skip, w, om * tile[(lloc0 + 1) * 68 + eloc]);
        o.z = fmaf(skip, w, om * tile[(lloc0 + 2) * 68 + eloc]);
        o.w = fmaf(skip, w, om * tile[(lloc0 + 3) * 68 + eloc]);
        const size_t off = (size_t)be * Lv + lt * 64 + lloc0;
        *(float4*)(out_ew  + off) = o;
        *(float4*)(out_ei0 + off) = make_float4(sv, sv, sv, sv);
        *(float4*)(out_ei1 + off) = make_float4(dv, dv, dv, dv);
    }
}

// Fallback ei broadcast kernel (only used if ws too small for probs buffer)
__global__ __launch_bounds__(256) void ei_kernel(
    const int* __restrict__ eidx, float* __restrict__ out)
{
    const int blk = blockIdx.x;            // 0..8191  (c*4096 + j)
    const int c = blk >> 12;
    const int j = blk & 4095;
    const float v = (float)eidx[c * BE + j];
    float4 o = make_float4(v, v, v, v);
    *(float4*)(out + (size_t)blk * 1024 + threadIdx.x * 4) = o;
}

// ---------------------------------------------------------------------------
extern "C" void kernel_launch(void* const* d_in, const int* in_sizes, int n_in,
                              void* d_out, int out_size, void* d_ws, size_t ws_size,
                              hipStream_t stream)
{
    const float* hs   = (const float*)d_in[0];
    const int*   eidx = (const int*)d_in[1];
    const float* ew   = (const float*)d_in[2];
    const float* Wq   = (const float*)d_in[3];
    const float* bq   = (const float*)d_in[4];
    const float* Wk   = (const float*)d_in[5];
    // d_in[6] = bk: provably unused (cancels in softmax)
    const float* skip = (const float*)d_in[7];

    char* wsb = (char*)d_ws;
    __bf16* Mb   = (__bf16*)wsb;                       // 65536 bf16 = 128 KiB
    float*  rv   = (float*)(wsb + 131072);             // 256 fp32 = 1 KiB
    float*  probs = (float*)(wsb + 132096);            // 4M fp32 = 16 MiB
    const size_t need = 132096 + (size_t)Bv * Lv * Ev * sizeof(float);

    precompute_kernel<<<dim3(257), dim3(256), 0, stream>>>(Wq, Wk, bq, Mb, rv);

    if (ws_size >= need) {
        edge_main<true><<<dim3(Bv * Lv), dim3(256), 0, stream>>>(
            hs, eidx, ew, skip, Mb, rv, probs);
        output_kernel<<<dim3(16, 16, 4), dim3(256), 0, stream>>>(
            probs, eidx, ew, skip, (float*)d_out);
    } else {
        float* out_ew = (float*)d_out + 2 * EI_PLANE;
        edge_main<false><<<dim3(Bv * Lv), dim3(256), 0, stream>>>(
            hs, eidx, ew, skip, Mb, rv, out_ew);
        ei_kernel<<<dim3(2 * BE), dim3(256), 0, stream>>>(eidx, (float*)d_out);
    }
}